// Round 1
// baseline (2752.545 us; speedup 1.0000x reference)
//
#include <hip/hip_runtime.h>
#include <math.h>

#define NS 1024
#define NA 2048
#define NRD 32768
#define CIN 16
#define CC 32
#define LL 150
#define LC 75

// ---------------------------------------------------------------------------
// K1: conv1d(k=5,pad=2,stride=1) + ReLU + sum over 16 reads -> red[a][32][150]
// block = 256 (thread -> c = tid&31, l-group = tid>>5 covering 19 l each)
// ---------------------------------------------------------------------------
__global__ __launch_bounds__(256) void k_conv_sum(const float* __restrict__ x,
                                                  const float* __restrict__ w,
                                                  float* __restrict__ red) {
  __shared__ float xs[CIN][156];     // [ic][l+2], zero pad at 0,1 and 152..155
  __shared__ float ws[CIN][5][CC];   // [ic][k][c] -> lanes read consecutive c
  const int a = blockIdx.x;
  const int tid = threadIdx.x;

  for (int i = tid; i < CIN * 5 * CC; i += 256) {
    int c = i & 31; int kk = i >> 5; int ic = kk / 5; int k = kk - ic * 5;
    ws[ic][k][c] = w[c * (CIN * 5) + ic * 5 + k];
  }
  if (tid < CIN) {
    xs[tid][0] = 0.f; xs[tid][1] = 0.f;
    xs[tid][152] = 0.f; xs[tid][153] = 0.f; xs[tid][154] = 0.f; xs[tid][155] = 0.f;
  }

  const int c = tid & 31;
  const int lg = tid >> 5;
  const int l0 = lg * 19;                       // 8*19 = 152 covers 150
  const int nl = (LL - l0 < 19) ? (LL - l0) : 19;

  float acc[19];
#pragma unroll
  for (int j = 0; j < 19; ++j) acc[j] = 0.f;

  for (int r = 0; r < 16; ++r) {
    __syncthreads();                            // protect xs vs previous readers
    const float* xr = x + (size_t)(a * 16 + r) * (CIN * LL);
    for (int i = tid; i < CIN * LL; i += 256) {
      int ic = i / LL; int l = i - ic * LL;
      xs[ic][l + 2] = xr[i];
    }
    __syncthreads();

    float v[19];
#pragma unroll
    for (int j = 0; j < 19; ++j) v[j] = 0.f;
    for (int ic = 0; ic < CIN; ++ic) {
      float w0 = ws[ic][0][c], w1 = ws[ic][1][c], w2 = ws[ic][2][c],
            w3 = ws[ic][3][c], w4 = ws[ic][4][c];
      float xw[23];
#pragma unroll
      for (int i = 0; i < 23; ++i) xw[i] = xs[ic][l0 + i];
#pragma unroll
      for (int j = 0; j < 19; ++j)
        v[j] += w0 * xw[j] + w1 * xw[j + 1] + w2 * xw[j + 2] + w3 * xw[j + 3] + w4 * xw[j + 4];
    }
#pragma unroll
    for (int j = 0; j < 19; ++j) acc[j] += fmaxf(v[j], 0.f);
  }

  float* out = red + (size_t)a * (CC * LL) + c * LL + l0;
  for (int j = 0; j < nl; ++j) out[j] = acc[j];
}

// ---------------------------------------------------------------------------
// K2: red2[a][c][l] = relu(sum_{c2<64} comb_w[c][c2] * cat(red0,red1)[a][c2][l])
// written IN PLACE over red0 (block stages its own slice in LDS first)
// ---------------------------------------------------------------------------
__global__ __launch_bounds__(256) void k_comb(const float* __restrict__ red0,
                                              const float* __restrict__ red1,
                                              const float* __restrict__ cw,
                                              float* __restrict__ out) {
  __shared__ float ins[64][152];
  __shared__ float cwl[64][CC];   // [c2][c]
  const int a = blockIdx.x;
  const int tid = threadIdx.x;

  for (int i = tid; i < 64 * CC; i += 256) {
    int c = i & 31; int c2 = i >> 5;
    cwl[c2][c] = cw[c * 64 + c2];
  }
  for (int i = tid; i < CC * LL; i += 256) {
    int c2 = i / LL; int l = i - c2 * LL;
    ins[c2][l] = red0[(size_t)a * (CC * LL) + i];
    ins[32 + c2][l] = red1[(size_t)a * (CC * LL) + i];
  }
  __syncthreads();

  const int c = tid & 31;
  const int lg = tid >> 5;
  const int l0 = lg * 19;
  const int nl = (LL - l0 < 19) ? (LL - l0) : 19;
  float v[19];
#pragma unroll
  for (int j = 0; j < 19; ++j) v[j] = 0.f;
  for (int c2 = 0; c2 < 64; ++c2) {
    float wv = cwl[c2][c];
#pragma unroll
    for (int j = 0; j < 19; ++j) v[j] += wv * ins[c2][l0 + j];
  }
  float* o = out + (size_t)a * (CC * LL) + c * LL + l0;
  for (int j = 0; j < nl; ++j) o[j] = fmaxf(v[j], 0.f);
}

// ---------------------------------------------------------------------------
// K3: compressor conv (k=3, dilation=2, stride=2, pad=2) + ReLU
// site_mode: input is src[2n] + src[2n+1] (reduce_slots over 2 alleles)
// out[n][c][j] = relu(sum_{ic,t} w[c][ic][t] * in[2j+2t-2]), j in [0,75)
// ---------------------------------------------------------------------------
__global__ __launch_bounds__(256) void k_compress(const float* __restrict__ src,
                                                  const float* __restrict__ w,
                                                  float* __restrict__ dst,
                                                  int site_mode) {
  __shared__ float ins[CC][164];    // [ic][pos+2]; valid 0..152, rest garbage-ok
  __shared__ float ws[CC][3][CC];   // [ic][t][c]
  const int n = blockIdx.x;
  const int tid = threadIdx.x;

  for (int i = tid; i < CC * 3 * CC; i += 256) {
    int c = i & 31; int kk = i >> 5; int ic = kk / 3; int t = kk - ic * 3;
    ws[ic][t][c] = w[c * (CC * 3) + ic * 3 + t];
  }
  if (tid < CC) { ins[tid][0] = 0.f; ins[tid][1] = 0.f; ins[tid][152] = 0.f; ins[tid][153] = 0.f; }

  if (site_mode) {
    const float* s0 = src + (size_t)(2 * n) * (CC * LL);
    const float* s1 = src + (size_t)(2 * n + 1) * (CC * LL);
    for (int i = tid; i < CC * LL; i += 256) {
      int ic = i / LL; int l = i - ic * LL;
      ins[ic][l + 2] = s0[i] + s1[i];
    }
  } else {
    const float* s0 = src + (size_t)n * (CC * LL);
    for (int i = tid; i < CC * LL; i += 256) {
      int ic = i / LL; int l = i - ic * LL;
      ins[ic][l + 2] = s0[i];
    }
  }
  __syncthreads();

  const int c = tid & 31;
  const int jg = tid >> 5;
  const int j0 = jg * 10;                      // 8*10 = 80 covers 75
  const int nj = (LC - j0 < 10) ? (LC - j0) : 10;
  float v[10];
#pragma unroll
  for (int j = 0; j < 10; ++j) v[j] = 0.f;
  for (int ic = 0; ic < CC; ++ic) {
    float w0 = ws[ic][0][c], w1 = ws[ic][1][c], w2 = ws[ic][2][c];
    float xw[12];
#pragma unroll
    for (int i = 0; i < 12; ++i) xw[i] = ins[ic][2 * j0 + 2 * i];
#pragma unroll
    for (int j = 0; j < 10; ++j) v[j] += w0 * xw[j] + w1 * xw[j + 1] + w2 * xw[j + 2];
  }
  float* o = dst + (size_t)n * (CC * LC) + c * LC + j0;
  for (int j = 0; j < nj; ++j) o[j] = fmaxf(v[j], 0.f);
}

// ---------------------------------------------------------------------------
// K4: fused cross-attention per allele
//  kv = [cfs0[s] | cfa[2s]+cfa[2s+1]], q=wq@cfa, k=wk@kv, v=wv@kv
//  scores -> softmax -> ctx; e[a][j] = sum_c wo[j][c] * mean_l(cfa+ctx)[c][l]
// ---------------------------------------------------------------------------
__global__ __launch_bounds__(256) void k_attn(const float* __restrict__ cfa,
                                              const float* __restrict__ cfs0,
                                              const float* __restrict__ wq,
                                              const float* __restrict__ wk,
                                              const float* __restrict__ wv,
                                              const float* __restrict__ wo,
                                              float* __restrict__ eout) {
  __shared__ float cf[CC][77];
  __shared__ float qb[CC][77];      // becomes (cfa + ctx) after row loop
  __shared__ float kvb[CC][153];
  __shared__ float kb[CC][153];
  __shared__ float vb[CC][153];
  __shared__ float wqs[CC][CC], wks[CC][CC], wvs[CC][CC];  // [in][out]
  __shared__ float rowp[8][LL];
  __shared__ float sbuf[CC];
  const int a = blockIdx.x;
  const int s = a >> 1;
  const int tid = threadIdx.x;

  for (int i = tid; i < CC * CC; i += 256) {
    int o = i & 31, ii = i >> 5;
    wqs[ii][o] = wq[o * CC + ii];
    wks[ii][o] = wk[o * CC + ii];
    wvs[ii][o] = wv[o * CC + ii];
  }
  for (int i = tid; i < CC * LC; i += 256) {
    int c = i / LC, l = i - c * LC;
    cf[c][l] = cfa[(size_t)a * (CC * LC) + i];
    kvb[c][l] = cfs0[(size_t)s * (CC * LC) + i];
    kvb[c][LC + l] = cfa[(size_t)(2 * s) * (CC * LC) + i] + cfa[(size_t)(2 * s + 1) * (CC * LC) + i];
  }
  __syncthreads();

  const int o = tid & 31;
  {
    float wcol[CC];
#pragma unroll
    for (int i2 = 0; i2 < CC; ++i2) wcol[i2] = wqs[i2][o];
    for (int idx = tid; idx < CC * LC; idx += 256) {
      int l = idx >> 5;
      float acc2 = 0.f;
#pragma unroll
      for (int i2 = 0; i2 < CC; ++i2) acc2 += wcol[i2] * cf[i2][l];
      qb[o][l] = acc2;
    }
  }
  {
    float wcol[CC];
#pragma unroll
    for (int i2 = 0; i2 < CC; ++i2) wcol[i2] = wks[i2][o];
    for (int idx = tid; idx < CC * 2 * LC; idx += 256) {
      int m = idx >> 5;
      float acc2 = 0.f;
#pragma unroll
      for (int i2 = 0; i2 < CC; ++i2) acc2 += wcol[i2] * kvb[i2][m];
      kb[o][m] = acc2;
    }
  }
  {
    float wcol[CC];
#pragma unroll
    for (int i2 = 0; i2 < CC; ++i2) wcol[i2] = wvs[i2][o];
    for (int idx = tid; idx < CC * 2 * LC; idx += 256) {
      int m = idx >> 5;
      float acc2 = 0.f;
#pragma unroll
      for (int i2 = 0; i2 < CC; ++i2) acc2 += wcol[i2] * kvb[i2][m];
      vb[o][m] = acc2;
    }
  }
  __syncthreads();

  const int g = tid >> 5;     // row group: 8 groups of 32 lanes
  const int t = tid & 31;
  const float scale = 0.17677669529663687f;   // 1/sqrt(32)
  for (int lrow = g; lrow < LC; lrow += 8) {
    float qcol[CC];
#pragma unroll
    for (int c2 = 0; c2 < CC; ++c2) qcol[c2] = qb[c2][lrow];
    float sc[5];
#pragma unroll
    for (int u = 0; u < 5; ++u) {
      int m = t + 32 * u;
      if (m < LL) {
        float acc2 = 0.f;
#pragma unroll
        for (int c2 = 0; c2 < CC; ++c2) acc2 += qcol[c2] * kb[c2][m];
        sc[u] = acc2 * scale;
      } else sc[u] = -1e30f;
    }
    float mx = sc[0];
#pragma unroll
    for (int u = 1; u < 5; ++u) mx = fmaxf(mx, sc[u]);
#pragma unroll
    for (int off = 16; off > 0; off >>= 1) mx = fmaxf(mx, __shfl_xor(mx, off, 32));
    float p[5]; float sum = 0.f;
#pragma unroll
    for (int u = 0; u < 5; ++u) {
      p[u] = (t + 32 * u < LL) ? __expf(sc[u] - mx) : 0.f;
      sum += p[u];
    }
#pragma unroll
    for (int off = 16; off > 0; off >>= 1) sum += __shfl_xor(sum, off, 32);
#pragma unroll
    for (int u = 0; u < 5; ++u) {
      int m = t + 32 * u;
      if (m < LL) rowp[g][m] = p[u];
    }
    float inv = 1.f / sum;
    float acc2 = 0.f;
#pragma unroll 10
    for (int m = 0; m < LL; ++m) acc2 += rowp[g][m] * vb[t][m];
    qb[t][lrow] = cf[t][lrow] + acc2 * inv;   // octx, in place of q (row done)
  }
  __syncthreads();

  if (tid < CC) {
    float s2 = 0.f;
    for (int l = 0; l < LC; ++l) s2 += qb[tid][l];
    sbuf[tid] = s2 * (1.f / 75.f);
  }
  __syncthreads();
  if (tid < 2) {
    float e = 0.f;
#pragma unroll
    for (int c2 = 0; c2 < CC; ++c2) e += wo[tid * CC + c2] * sbuf[c2];
    eout[a * 2 + tid] = e;
  }
}

// ---------------------------------------------------------------------------
// K5: meta head per site: feat = [mean_l cfs0[s] | mean_l (cfa[2s]+cfa[2s+1])]
//     out = softmax(feat @ meta_w.T + meta_b)
// ---------------------------------------------------------------------------
__global__ __launch_bounds__(64) void k_meta(const float* __restrict__ cfs0,
                                             const float* __restrict__ cfa2,
                                             const float* __restrict__ mw,
                                             const float* __restrict__ mb,
                                             float* __restrict__ mout) {
  __shared__ float feat[64];
  __shared__ float lgt[3];
  const int s = blockIdx.x;
  const int tid = threadIdx.x;
  float f = 0.f;
  if (tid < 32) {
    const float* p = cfs0 + (size_t)s * (CC * LC) + tid * LC;
    for (int l = 0; l < LC; ++l) f += p[l];
  } else {
    const float* p0 = cfa2 + (size_t)(2 * s) * (CC * LC) + (tid - 32) * LC;
    const float* p1 = cfa2 + (size_t)(2 * s + 1) * (CC * LC) + (tid - 32) * LC;
    for (int l = 0; l < LC; ++l) f += p0[l] + p1[l];
  }
  feat[tid] = f * (1.f / 75.f);
  __syncthreads();
  if (tid < 3) {
    float acc2 = mb[tid];
    for (int c2 = 0; c2 < 64; ++c2) acc2 += mw[tid * 64 + c2] * feat[c2];
    lgt[tid] = acc2;
  }
  __syncthreads();
  if (tid < 3) {
    float mx = fmaxf(lgt[0], fmaxf(lgt[1], lgt[2]));
    float e0 = __expf(lgt[0] - mx), e1 = __expf(lgt[1] - mx), e2 = __expf(lgt[2] - mx);
    mout[s * 3 + tid] = __expf(lgt[tid] - mx) / (e0 + e1 + e2);
  }
}

// ---------------------------------------------------------------------------
extern "C" void kernel_launch(void* const* d_in, const int* in_sizes, int n_in,
                              void* d_out, int out_size, void* d_ws, size_t ws_size,
                              hipStream_t stream) {
  const float* t0      = (const float*)d_in[0];
  const float* t1      = (const float*)d_in[1];
  const float* conv0_w = (const float*)d_in[2];
  const float* conv1_w = (const float*)d_in[3];
  const float* comp0_w = (const float*)d_in[4];
  const float* comp1_w = (const float*)d_in[5];
  const float* comp2_w = (const float*)d_in[6];
  const float* xq0 = (const float*)d_in[7];
  const float* xk0 = (const float*)d_in[8];
  const float* xv0 = (const float*)d_in[9];
  const float* xo0 = (const float*)d_in[10];
  const float* xq1 = (const float*)d_in[11];
  const float* xk1 = (const float*)d_in[12];
  const float* xv1 = (const float*)d_in[13];
  const float* xo1 = (const float*)d_in[14];
  const float* xq2 = (const float*)d_in[15];
  const float* xk2 = (const float*)d_in[16];
  const float* xv2 = (const float*)d_in[17];
  const float* xo2 = (const float*)d_in[18];
  const float* comb_w = (const float*)d_in[19];
  const float* meta_w = (const float*)d_in[20];
  const float* meta_b = (const float*)d_in[21];
  // d_in[22..24]: num_alleles_per_site / num_reads (constant 2 / 16, hard-coded)

  float* wsf  = (float*)d_ws;
  float* red0 = wsf;                              // 2048*4800 floats
  float* red1 = red0 + (size_t)NA * CC * LL;      // 2048*4800
  float* cfa  = red1 + (size_t)NA * CC * LL;      // 2048*2400
  float* cfs0 = cfa + (size_t)NA * CC * LC;       // 1024*2400  (total ~108 MB)
  float* out  = (float*)d_out;

  // stage 1: conv + relu + segmented sum over reads
  k_conv_sum<<<NA, 256, 0, stream>>>(t0, conv0_w, red0);
  k_conv_sum<<<NA, 256, 0, stream>>>(t1, conv1_w, red1);

  // branch 0
  k_compress<<<NA, 256, 0, stream>>>(red0, comp0_w, cfa, 0);
  k_compress<<<NS, 256, 0, stream>>>(red0, comp0_w, cfs0, 1);
  k_attn<<<NA, 256, 0, stream>>>(cfa, cfs0, xq0, xk0, xv0, xo0, out + 0);

  // branch 1
  k_compress<<<NA, 256, 0, stream>>>(red1, comp1_w, cfa, 0);
  k_compress<<<NS, 256, 0, stream>>>(red1, comp1_w, cfs0, 1);
  k_attn<<<NA, 256, 0, stream>>>(cfa, cfs0, xq1, xk1, xv1, xo1, out + 2 * NA);

  // branch 2: red2 = relu(comb_w @ [red0|red1]) written in place over red0
  k_comb<<<NA, 256, 0, stream>>>(red0, red1, comb_w, red0);
  k_compress<<<NA, 256, 0, stream>>>(red0, comp2_w, cfa, 0);
  k_compress<<<NS, 256, 0, stream>>>(red0, comp2_w, cfs0, 1);
  k_attn<<<NA, 256, 0, stream>>>(cfa, cfs0, xq2, xk2, xv2, xo2, out + 4 * NA);

  // meta head (uses branch-2 cfs0 and cfa)
  k_meta<<<NS, 64, 0, stream>>>(cfs0, cfa, meta_w, meta_b, out + 6 * NA);
}

// Round 2
// 2144.626 us; speedup vs baseline: 1.2835x; 1.2835x over previous
//
#include <hip/hip_runtime.h>
#include <math.h>

#define NS 1024
#define NA 2048
#define CIN 16
#define CC 32
#define LL 150
#define LC 75

typedef __attribute__((ext_vector_type(8))) short short8;
typedef __attribute__((ext_vector_type(4))) float float4v;

__device__ __forceinline__ unsigned short f2bf(float f) {
  // round-to-nearest-even fp32 -> bf16
  unsigned int u = __float_as_uint(f);
  unsigned int r = (u + 0x7FFFu + ((u >> 16) & 1u)) >> 16;
  return (unsigned short)r;
}

// ---------------------------------------------------------------------------
// K1: conv1d(k=5,pad=2) + ReLU + sum over 16 reads, as bf16 MFMA implicit GEMM
// Per read r: C(32x150) = W(32x80) * X(80x150); red += relu(C).
// K=80 -> 3 steps of 32 = (16 ic x 2 taps): step s covers taps {2s, 2s+1}
// (tap 5 in step 2 is zero-padded in A).
// LDS im2col, pair-duplicated: xs2[p][2*ic+t] = px[ic][p+t], px[q]=x[q-2] (0-pad)
//  -> B-frag for lane (16x16x32): 8 contiguous bf16 at xs2[n0+(lane&15)+2s][8*(lane>>4)]
// Block = 128 threads (2 waves), wave w owns N-columns [80w, 80w+80).
// ---------------------------------------------------------------------------
__global__ __launch_bounds__(128) void k_conv_sum_mfma(const float* __restrict__ x,
                                                       const float* __restrict__ w,
                                                       float* __restrict__ red) {
  __shared__ unsigned short xs2[168][32];   // 10.5 KB
  const int a = blockIdx.x;
  const int tid = threadIdx.x;
  const int lane = tid & 63;
  const int wv = tid >> 6;

  // zero once: dead pad region stays 0 forever; live region rewritten per read
  for (int i = tid; i < 168 * 16; i += 128) ((unsigned int*)xs2)[i] = 0u;

  // A-fragments (weights) -> registers. lane holds A[m=lane&15][k=8*(lane>>4)+j]
  short8 afr[2][3];
  {
    const int mrow = lane & 15;
    const int h = lane >> 4;
    for (int mt = 0; mt < 2; ++mt) {
      const int c = mt * 16 + mrow;
      for (int s = 0; s < 3; ++s) {
        short8 f;
#pragma unroll
        for (int j = 0; j < 8; ++j) {
          int ic = 4 * h + (j >> 1);
          int tap = 2 * s + (j & 1);
          float wval = (tap < 5) ? w[c * 80 + ic * 5 + tap] : 0.f;
          f[j] = (short)f2bf(wval);
        }
        afr[mt][s] = f;
      }
    }
  }

  float4v sum[2][5];
#pragma unroll
  for (int mt = 0; mt < 2; ++mt)
#pragma unroll
    for (int nt = 0; nt < 5; ++nt) sum[mt][nt] = (float4v)(0.f);

  const int nbase = wv * 80;
  const int nrow = lane & 15;
  const int h8 = (lane >> 4) * 8;
  const float4v zf = (float4v)(0.f);

  for (int r = 0; r < 16; ++r) {
    __syncthreads();
    const float* xr = x + (size_t)(a * 16 + r) * (CIN * LL);
    for (int i = tid; i < CIN * LL; i += 128) {
      int ic = i / LL, l = i - ic * LL;
      unsigned short b = f2bf(xr[i]);
      xs2[l + 2][2 * ic] = b;        // t=0 slot: px[l+2]
      xs2[l + 1][2 * ic + 1] = b;    // t=1 slot: px[(l+1)+1]
    }
    __syncthreads();

    float4v acc[2][5];
#pragma unroll
    for (int s = 0; s < 3; ++s) {
#pragma unroll
      for (int nt = 0; nt < 5; ++nt) {
        const int p = nbase + nt * 16 + nrow + 2 * s;
        short8 bfrag = *(const short8*)&xs2[p][h8];
#pragma unroll
        for (int mt = 0; mt < 2; ++mt) {
          acc[mt][nt] = __builtin_amdgcn_mfma_f32_16x16x32_bf16(
              afr[mt][s], bfrag, (s == 0) ? zf : acc[mt][nt], 0, 0, 0);
        }
      }
    }
#pragma unroll
    for (int mt = 0; mt < 2; ++mt)
#pragma unroll
      for (int nt = 0; nt < 5; ++nt)
#pragma unroll
        for (int q = 0; q < 4; ++q) sum[mt][nt][q] += fmaxf(acc[mt][nt][q], 0.f);
  }

  // C/D layout (16x16): col = lane&15 -> l, row = (lane>>4)*4+reg -> c
  const int ccol = lane & 15;
  const int crow4 = (lane >> 4) * 4;
  for (int mt = 0; mt < 2; ++mt)
    for (int nt = 0; nt < 5; ++nt) {
      int l = nbase + nt * 16 + ccol;
      if (l < LL) {
#pragma unroll
        for (int q = 0; q < 4; ++q) {
          int c = mt * 16 + crow4 + q;
          red[(size_t)a * (CC * LL) + c * LL + l] = sum[mt][nt][q];
        }
      }
    }
}

// ---------------------------------------------------------------------------
// K2: red2 = relu(comb_w @ [red0|red1]) in place over red0
// ---------------------------------------------------------------------------
__global__ __launch_bounds__(256) void k_comb(const float* __restrict__ red0,
                                              const float* __restrict__ red1,
                                              const float* __restrict__ cw,
                                              float* __restrict__ out) {
  __shared__ float ins[64][152];
  __shared__ float cwl[64][CC];
  const int a = blockIdx.x;
  const int tid = threadIdx.x;

  for (int i = tid; i < 64 * CC; i += 256) {
    int c = i & 31; int c2 = i >> 5;
    cwl[c2][c] = cw[c * 64 + c2];
  }
  for (int i = tid; i < CC * LL; i += 256) {
    int c2 = i / LL; int l = i - c2 * LL;
    ins[c2][l] = red0[(size_t)a * (CC * LL) + i];
    ins[32 + c2][l] = red1[(size_t)a * (CC * LL) + i];
  }
  __syncthreads();

  const int c = tid & 31;
  const int lg = tid >> 5;
  const int l0 = lg * 19;
  const int nl = (LL - l0 < 19) ? (LL - l0) : 19;
  float v[19];
#pragma unroll
  for (int j = 0; j < 19; ++j) v[j] = 0.f;
  for (int c2 = 0; c2 < 64; ++c2) {
    float wv = cwl[c2][c];
#pragma unroll
    for (int j = 0; j < 19; ++j) v[j] += wv * ins[c2][l0 + j];
  }
  float* o = out + (size_t)a * (CC * LL) + c * LL + l0;
  for (int j = 0; j < nl; ++j) o[j] = fmaxf(v[j], 0.f);
}

// ---------------------------------------------------------------------------
// K3: compressor conv (k=3, dil=2, stride=2, pad=2) + ReLU; site_mode sums pairs
// ---------------------------------------------------------------------------
__global__ __launch_bounds__(256) void k_compress(const float* __restrict__ src,
                                                  const float* __restrict__ w,
                                                  float* __restrict__ dst,
                                                  int site_mode) {
  __shared__ float ins[CC][164];
  __shared__ float ws[CC][3][CC];
  const int n = blockIdx.x;
  const int tid = threadIdx.x;

  for (int i = tid; i < CC * 3 * CC; i += 256) {
    int c = i & 31; int kk = i >> 5; int ic = kk / 3; int t = kk - ic * 3;
    ws[ic][t][c] = w[c * (CC * 3) + ic * 3 + t];
  }
  if (tid < CC) { ins[tid][0] = 0.f; ins[tid][1] = 0.f; ins[tid][152] = 0.f; ins[tid][153] = 0.f; }

  if (site_mode) {
    const float* s0 = src + (size_t)(2 * n) * (CC * LL);
    const float* s1 = src + (size_t)(2 * n + 1) * (CC * LL);
    for (int i = tid; i < CC * LL; i += 256) {
      int ic = i / LL; int l = i - ic * LL;
      ins[ic][l + 2] = s0[i] + s1[i];
    }
  } else {
    const float* s0 = src + (size_t)n * (CC * LL);
    for (int i = tid; i < CC * LL; i += 256) {
      int ic = i / LL; int l = i - ic * LL;
      ins[ic][l + 2] = s0[i];
    }
  }
  __syncthreads();

  const int c = tid & 31;
  const int jg = tid >> 5;
  const int j0 = jg * 10;
  const int nj = (LC - j0 < 10) ? (LC - j0) : 10;
  float v[10];
#pragma unroll
  for (int j = 0; j < 10; ++j) v[j] = 0.f;
  for (int ic = 0; ic < CC; ++ic) {
    float w0 = ws[ic][0][c], w1 = ws[ic][1][c], w2 = ws[ic][2][c];
    float xw[12];
#pragma unroll
    for (int i = 0; i < 12; ++i) xw[i] = ins[ic][2 * j0 + 2 * i];
#pragma unroll
    for (int j = 0; j < 10; ++j) v[j] += w0 * xw[j] + w1 * xw[j + 1] + w2 * xw[j + 2];
  }
  float* o = dst + (size_t)n * (CC * LC) + c * LC + j0;
  for (int j = 0; j < nj; ++j) o[j] = fmaxf(v[j], 0.f);
}

// ---------------------------------------------------------------------------
// K4 v2: fused cross-attention per allele. LDS arena 72.7 KB -> 2 blocks/CU.
// Aliasing (phase1 -> phase2): wq-region -> rowp+sbuf; kv-region -> vb.
// k stored transposed kbT[m][34] (2-way-free float2 score reads);
// v stored vb[c][150] (2-way-free float2 PV reads).
// ---------------------------------------------------------------------------
#define OFF_CF   0        // cf[32][75]
#define OFF_QB   2400     // qb[32][75]   (q, then cfa+ctx)
#define OFF_WQ   4800     // wq[32][32] in-major   | phase2: rowp[8][152]
#define OFF_WK   5824     // wk[32][32]            | phase2: sbuf@6016
#define OFF_WV   6848     // wv[32][32]
#define OFF_ROWP 4800
#define OFF_SBUF 6016
#define OFF_KV   7872     // kv[32][152]           | phase2: vb[32][150]
#define OFF_VB   7872
#define OFF_KBT  12736    // kbT[160][34]
#define ARENA_F  18176

__global__ __launch_bounds__(256) void k_attn(const float* __restrict__ cfa,
                                              const float* __restrict__ cfs0,
                                              const float* __restrict__ wq,
                                              const float* __restrict__ wk,
                                              const float* __restrict__ wv,
                                              const float* __restrict__ wo,
                                              float* __restrict__ eout) {
  __shared__ float arena[ARENA_F];
  const int a = blockIdx.x;
  const int s = a >> 1;
  const int tid = threadIdx.x;
  const int o = tid & 31;

  // ---- phase 1: stage weights, cf, kv ----
  for (int i = tid; i < CC * CC; i += 256) {
    int oo = i & 31, ii = i >> 5;
    arena[OFF_WQ + ii * 32 + oo] = wq[oo * CC + ii];
    arena[OFF_WK + ii * 32 + oo] = wk[oo * CC + ii];
    arena[OFF_WV + ii * 32 + oo] = wv[oo * CC + ii];
  }
  for (int i = tid; i < CC * LC; i += 256) {
    int c = i / LC, l = i - c * LC;
    arena[OFF_CF + c * 75 + l] = cfa[(size_t)a * (CC * LC) + i];
    arena[OFF_KV + c * 152 + l] = cfs0[(size_t)s * (CC * LC) + i];
    arena[OFF_KV + c * 152 + 75 + l] =
        cfa[(size_t)(2 * s) * (CC * LC) + i] + cfa[(size_t)(2 * s + 1) * (CC * LC) + i];
  }
  __syncthreads();

  // ---- phase 1b: q -> qb (LDS); k,v -> registers ----
  float wkc[32], wvc[32];
#pragma unroll
  for (int ii = 0; ii < 32; ++ii) {
    wkc[ii] = arena[OFF_WK + ii * 32 + o];
    wvc[ii] = arena[OFF_WV + ii * 32 + o];
  }
  for (int idx = tid; idx < CC * LC; idx += 256) {
    int l = idx >> 5;
    float acc = 0.f;
#pragma unroll
    for (int ii = 0; ii < 32; ++ii)
      acc += arena[OFF_WQ + ii * 32 + o] * arena[OFF_CF + ii * 75 + l];
    arena[OFF_QB + o * 75 + l] = acc;
  }
  float kr[19], vr[19];
  {
    int cnt = 0;
    for (int idx = tid; idx < CC * LL; idx += 256, ++cnt) {
      int m = idx >> 5;
      float ka = 0.f, va = 0.f;
#pragma unroll
      for (int ii = 0; ii < 32; ++ii) {
        float kvv = arena[OFF_KV + ii * 152 + m];
        ka += wkc[ii] * kvv;
        va += wvc[ii] * kvv;
      }
      kr[cnt] = ka; vr[cnt] = va;
    }
  }
  __syncthreads();   // all kv reads done; safe to overwrite kv-region with vb
  {
    int cnt = 0;
    for (int idx = tid; idx < CC * LL; idx += 256, ++cnt) {
      int m = idx >> 5;
      arena[OFF_KBT + m * 34 + o] = kr[cnt];
      arena[OFF_VB + o * 150 + m] = vr[cnt];
    }
  }
  __syncthreads();

  // ---- phase 2: per-row scores -> softmax -> PV ----
  const int g = tid >> 5;
  const int t = tid & 31;
  const float scale = 0.17677669529663687f;   // 1/sqrt(32)
  for (int lrow = g; lrow < LC; lrow += 8) {
    float qc[32];
#pragma unroll
    for (int c2 = 0; c2 < 32; ++c2) qc[c2] = arena[OFF_QB + c2 * 75 + lrow];
    float sc[5];
#pragma unroll
    for (int u = 0; u < 5; ++u) {
      int m = t + 32 * u;
      if (m < LL) {
        float acc = 0.f;
#pragma unroll
        for (int c2 = 0; c2 < 32; c2 += 2) {
          float2 kk = *(const float2*)&arena[OFF_KBT + m * 34 + c2];
          acc += qc[c2] * kk.x + qc[c2 + 1] * kk.y;
        }
        sc[u] = acc * scale;
      } else sc[u] = -1e30f;
    }
    float mx = sc[0];
#pragma unroll
    for (int u = 1; u < 5; ++u) mx = fmaxf(mx, sc[u]);
#pragma unroll
    for (int off = 16; off > 0; off >>= 1) mx = fmaxf(mx, __shfl_xor(mx, off, 32));
    float p[5]; float ssum = 0.f;
#pragma unroll
    for (int u = 0; u < 5; ++u) {
      p[u] = (t + 32 * u < LL) ? __expf(sc[u] - mx) : 0.f;
      ssum += p[u];
    }
#pragma unroll
    for (int off = 16; off > 0; off >>= 1) ssum += __shfl_xor(ssum, off, 32);
#pragma unroll
    for (int u = 0; u < 5; ++u) {
      int m = t + 32 * u;
      if (m < LL) arena[OFF_ROWP + g * 152 + m] = p[u];
    }
    float inv = 1.f / ssum;
    float acc = 0.f;
#pragma unroll 5
    for (int mm = 0; mm < LL; mm += 2) {
      float2 pv = *(const float2*)&arena[OFF_ROWP + g * 152 + mm];
      float2 vv = *(const float2*)&arena[OFF_VB + t * 150 + mm];
      acc += pv.x * vv.x + pv.y * vv.y;
    }
    arena[OFF_QB + t * 75 + lrow] = arena[OFF_CF + t * 75 + lrow] + acc * inv;
  }
  __syncthreads();

  // ---- epilogue: mean over l, project with wo ----
  if (tid < CC) {
    float s2 = 0.f;
    for (int l = 0; l < LC; ++l) s2 += arena[OFF_QB + tid * 75 + l];
    arena[OFF_SBUF + tid] = s2 * (1.f / 75.f);
  }
  __syncthreads();
  if (tid < 2) {
    float e = 0.f;
#pragma unroll
    for (int c2 = 0; c2 < CC; ++c2) e += wo[tid * CC + c2] * arena[OFF_SBUF + c2];
    eout[a * 2 + tid] = e;
  }
}

// ---------------------------------------------------------------------------
// K5: meta head per site
// ---------------------------------------------------------------------------
__global__ __launch_bounds__(64) void k_meta(const float* __restrict__ cfs0,
                                             const float* __restrict__ cfa2,
                                             const float* __restrict__ mw,
                                             const float* __restrict__ mb,
                                             float* __restrict__ mout) {
  __shared__ float feat[64];
  __shared__ float lgt[3];
  const int s = blockIdx.x;
  const int tid = threadIdx.x;
  float f = 0.f;
  if (tid < 32) {
    const float* p = cfs0 + (size_t)s * (CC * LC) + tid * LC;
    for (int l = 0; l < LC; ++l) f += p[l];
  } else {
    const float* p0 = cfa2 + (size_t)(2 * s) * (CC * LC) + (tid - 32) * LC;
    const float* p1 = cfa2 + (size_t)(2 * s + 1) * (CC * LC) + (tid - 32) * LC;
    for (int l = 0; l < LC; ++l) f += p0[l] + p1[l];
  }
  feat[tid] = f * (1.f / 75.f);
  __syncthreads();
  if (tid < 3) {
    float acc2 = mb[tid];
    for (int c2 = 0; c2 < 64; ++c2) acc2 += mw[tid * 64 + c2] * feat[c2];
    lgt[tid] = acc2;
  }
  __syncthreads();
  if (tid < 3) {
    float mx = fmaxf(lgt[0], fmaxf(lgt[1], lgt[2]));
    float e0 = __expf(lgt[0] - mx), e1 = __expf(lgt[1] - mx), e2 = __expf(lgt[2] - mx);
    mout[s * 3 + tid] = __expf(lgt[tid] - mx) / (e0 + e1 + e2);
  }
}

// ---------------------------------------------------------------------------
extern "C" void kernel_launch(void* const* d_in, const int* in_sizes, int n_in,
                              void* d_out, int out_size, void* d_ws, size_t ws_size,
                              hipStream_t stream) {
  const float* t0      = (const float*)d_in[0];
  const float* t1      = (const float*)d_in[1];
  const float* conv0_w = (const float*)d_in[2];
  const float* conv1_w = (const float*)d_in[3];
  const float* comp0_w = (const float*)d_in[4];
  const float* comp1_w = (const float*)d_in[5];
  const float* comp2_w = (const float*)d_in[6];
  const float* xq0 = (const float*)d_in[7];
  const float* xk0 = (const float*)d_in[8];
  const float* xv0 = (const float*)d_in[9];
  const float* xo0 = (const float*)d_in[10];
  const float* xq1 = (const float*)d_in[11];
  const float* xk1 = (const float*)d_in[12];
  const float* xv1 = (const float*)d_in[13];
  const float* xo1 = (const float*)d_in[14];
  const float* xq2 = (const float*)d_in[15];
  const float* xk2 = (const float*)d_in[16];
  const float* xv2 = (const float*)d_in[17];
  const float* xo2 = (const float*)d_in[18];
  const float* comb_w = (const float*)d_in[19];
  const float* meta_w = (const float*)d_in[20];
  const float* meta_b = (const float*)d_in[21];

  float* wsf  = (float*)d_ws;
  float* red0 = wsf;
  float* red1 = red0 + (size_t)NA * CC * LL;
  float* cfa  = red1 + (size_t)NA * CC * LL;
  float* cfs0 = cfa + (size_t)NA * CC * LC;
  float* out  = (float*)d_out;

  k_conv_sum_mfma<<<NA, 128, 0, stream>>>(t0, conv0_w, red0);
  k_conv_sum_mfma<<<NA, 128, 0, stream>>>(t1, conv1_w, red1);

  k_compress<<<NA, 256, 0, stream>>>(red0, comp0_w, cfa, 0);
  k_compress<<<NS, 256, 0, stream>>>(red0, comp0_w, cfs0, 1);
  k_attn<<<NA, 256, 0, stream>>>(cfa, cfs0, xq0, xk0, xv0, xo0, out + 0);

  k_compress<<<NA, 256, 0, stream>>>(red1, comp1_w, cfa, 0);
  k_compress<<<NS, 256, 0, stream>>>(red1, comp1_w, cfs0, 1);
  k_attn<<<NA, 256, 0, stream>>>(cfa, cfs0, xq1, xk1, xv1, xo1, out + 2 * NA);

  k_comb<<<NA, 256, 0, stream>>>(red0, red1, comb_w, red0);
  k_compress<<<NA, 256, 0, stream>>>(red0, comp2_w, cfa, 0);
  k_compress<<<NS, 256, 0, stream>>>(red0, comp2_w, cfs0, 1);
  k_attn<<<NA, 256, 0, stream>>>(cfa, cfs0, xq2, xk2, xv2, xo2, out + 4 * NA);

  k_meta<<<NS, 64, 0, stream>>>(cfs0, cfa, meta_w, meta_b, out + 6 * NA);
}